// Round 19
// baseline (118.584 us; speedup 1.0000x reference)
//
#include <hip/hip_runtime.h>

// Problem constants (fixed by reference)
constexpr int Bn = 4, Cn = 64, Hn = 192, Wn = 640, HW = Hn * Wn;
constexpr int TH = 8, TW = 64;            // output tile per block
constexpr int SH = TH + 4;                // 12 tile+halo rows
constexpr int SW = TW + 4;                // 68 (even: float2 pair staging)
constexpr int NS = SH * SW;               // 816
constexpr int NP = NS / 2;                // 408 staging pairs
constexpr int PPR = SW / 2;               // 34 pairs per row
constexpr int NT = 512;                   // 1 output px/thread
constexpr int CH = 4;                     // channels staged per chunk
constexpr int NCHUNK = Cn / CH;           // 16
constexpr int DR = SH - 2;                // 10 forward-dot rows
constexpr int ND = DR * SW;               // 680 forward-domain pixels
constexpr int NPAIR = (DR / 2) * SW;      // 340 compute-pair threads
constexpr int ARENA = 12 * ND;            // 8160 floats = 32.6 KB

// Relaxed barrier (T4): ds-writes visible via lgkmcnt(0); global loads stay
// in flight across the barrier (no vmcnt(0) drain, unlike __syncthreads).
#define SYNC_RELAXED() do {                                   \
    asm volatile("s_waitcnt lgkmcnt(0)" ::: "memory");        \
    __builtin_amdgcn_s_barrier();                             \
    asm volatile("" ::: "memory");                            \
} while (0)

// ---------------------------------------------------------------------------
// MEASUREMENT PROBE: exactly the main kernel's global-load pattern (same
// grid, same per-thread addresses, all 64 channels), nothing else. Measures
// the pattern's pure HBM fetch rate at maximal memory-level parallelism,
// and warms L3 with precisely the real kernel's footprint.
// ---------------------------------------------------------------------------
__global__ __launch_bounds__(NT, 4) void fetch_probe(
    const float* __restrict__ pred)
{
    const int x0 = blockIdx.x * TW;
    const int y0 = blockIdx.y * TH;
    const int b  = blockIdx.z;
    const int tid = threadIdx.x;

    const bool hasS = (tid < NP);
    const int srow = tid / PPR;
    const int spc  = tid - srow * PPR;
    const int gy = y0 + srow - 2;
    const int gx = x0 + 2 * spc - 2;
    const bool okS = hasS && (gy >= 0) && (gy < Hn) && (gx >= 0) && (gx + 1 < Wn);
    const int goff = gy * Wn + gx;

    const float* predb = pred + (size_t)b * Cn * HW;
    float sx = 0.0f, sy = 0.0f;
    #pragma unroll 8
    for (int c = 0; c < Cn; ++c) {
        float2 v = make_float2(0.0f, 0.0f);
        if (okS) v = *reinterpret_cast<const float2*>(predb + c * HW + goff);
        sx += v.x;
        sy += v.y;
    }
    // keep loads live without any memory write (rule #17)
    asm volatile("" :: "v"(sx), "v"(sy));
}

// ---------------------------------------------------------------------------
// Real kernel: R15 verbatim (best known-good: 67.3 us headline).
// ---------------------------------------------------------------------------
// NOTE: min-waves-per-EU > 4 makes the allocator spill (R11). Keep 4.
__global__ __launch_bounds__(NT, 4) void guide_triplet_kernel(
    const float* __restrict__ pred,
    const int*   __restrict__ target,
    float* __restrict__ out)
{
    __shared__ float arena[ARENA];
    __shared__ float invnS[NS + 4];   // +4 pad: benign OOB publish reads
    __shared__ int   lblS[NS];

    const int x0 = blockIdx.x * TW;
    const int y0 = blockIdx.y * TH;
    const int b  = blockIdx.z;

    const int tid = threadIdx.x;
    const int tx  = tid & (TW - 1);   // 0..63
    const int ty  = tid >> 6;         // 0..7

    // ---- float2 pair staging geometry (1 pair/thread, tid < 408) ----
    const bool hasS = (tid < NP);
    const int srow = tid / PPR;               // 0..11
    const int spc  = tid - srow * PPR;        // 0..33
    const int gy = y0 + srow - 2;
    const int gx = x0 + 2 * spc - 2;          // even -> 8B aligned
    const bool okS = hasS && (gy >= 0) && (gy < Hn) && (gx >= 0) && (gx + 1 < Wn);
    const int goff = gy * Wn + gx;
    const int sidx = 2 * tid;                 // word index of the pair

    // ---- labels once (pad = -1) ----
    if (hasS) {
        int lx = -1, ly = -1;
        if (okS) {
            const int2 L = *reinterpret_cast<const int2*>(target + b * HW + goff);
            lx = L.x; ly = L.y;
        }
        lblS[sidx]     = lx;
        lblS[sidx + 1] = ly;
    }
    if (tid < 4) invnS[NS + tid] = 1.0f;      // init pad

    // ---- compute-pair mapping: thread -> pixels (rA,pc),(rA+1,pc) ----
    const bool isPair = (tid < NPAIR);
    const int pa = tid / SW;          // 0..4
    const int pc = tid - pa * SW;     // 0..67
    const int rA = 2 * pa;            // 0,2,4,6,8

    float ssx = 0.0f, ssy = 0.0f;
    float accA[12], accB[12];
    #pragma unroll
    for (int i = 0; i < 12; ++i) { accA[i] = 0.0f; accB[i] = 0.0f; }

    const float* predb = pred + (size_t)b * Cn * HW;

    float2 ldA[CH], ldB[CH];

#define LOADCHUNK(DST, CHUNK) do {                                          \
    _Pragma("unroll")                                                       \
    for (int cc = 0; cc < CH; ++cc) {                                       \
        const float* pc_ = predb + (size_t)((CHUNK) * CH + cc) * HW;        \
        float2 v = make_float2(0.f, 0.f);                                   \
        if (okS) v = *reinterpret_cast<const float2*>(pc_ + goff);          \
        DST[cc] = v;                                                        \
    } } while (0)

#define BODY(K, LD, KP2) {                                                  \
    float* sb = arena + ((K) & 1) * (CH * NS);                              \
    /* W(K): regs -> LDS (ds_write_b64), fold sumsq */                      \
    if (hasS) {                                                             \
        _Pragma("unroll")                                                   \
        for (int cc = 0; cc < CH; ++cc) {                                   \
            const float2 v = LD[cc];                                        \
            *reinterpret_cast<float2*>(&sb[cc * NS + sidx]) = v;            \
            ssx = fmaf(v.x, v.x, ssx);                                      \
            ssy = fmaf(v.y, v.y, ssy);                                      \
        } }                                                                 \
    SYNC_RELAXED();                                                         \
    /* L(K+2): depth-2 prefetch, in flight across relaxed barriers */       \
    if ((KP2) < NCHUNK) LOADCHUNK(LD, KP2);                                 \
    /* C(K): forward dots, 18 LDS words + 24 FMA per channel per pair */    \
    if (isPair) {                                                           \
        _Pragma("unroll")                                                   \
        for (int cc = 0; cc < CH; ++cc) {                                   \
            const float* s0 = sb + cc * NS + rA * SW + pc;                  \
            const float w00 = s0[0], w01 = s0[1], w02 = s0[2];              \
            const float* s1 = s0 + (SW - 2);                                \
            const float w10 = s1[0], w11 = s1[1], w12 = s1[2],              \
                        w13 = s1[3], w14 = s1[4];                           \
            const float* s2 = s1 + SW;                                      \
            const float w20 = s2[0], w21 = s2[1], w22 = s2[2],              \
                        w23 = s2[3], w24 = s2[4];                           \
            const float* s3 = s2 + SW;                                      \
            const float w30 = s3[0], w31 = s3[1], w32 = s3[2],              \
                        w33 = s3[3], w34 = s3[4];                           \
            accA[0]  = fmaf(w00, w01, accA[0]);                             \
            accA[1]  = fmaf(w00, w02, accA[1]);                             \
            accA[2]  = fmaf(w00, w10, accA[2]);                             \
            accA[3]  = fmaf(w00, w11, accA[3]);                             \
            accA[4]  = fmaf(w00, w12, accA[4]);                             \
            accA[5]  = fmaf(w00, w13, accA[5]);                             \
            accA[6]  = fmaf(w00, w14, accA[6]);                             \
            accA[7]  = fmaf(w00, w20, accA[7]);                             \
            accA[8]  = fmaf(w00, w21, accA[8]);                             \
            accA[9]  = fmaf(w00, w22, accA[9]);                             \
            accA[10] = fmaf(w00, w23, accA[10]);                            \
            accA[11] = fmaf(w00, w24, accA[11]);                            \
            accB[0]  = fmaf(w12, w13, accB[0]);                             \
            accB[1]  = fmaf(w12, w14, accB[1]);                             \
            accB[2]  = fmaf(w12, w20, accB[2]);                             \
            accB[3]  = fmaf(w12, w21, accB[3]);                             \
            accB[4]  = fmaf(w12, w22, accB[4]);                             \
            accB[5]  = fmaf(w12, w23, accB[5]);                             \
            accB[6]  = fmaf(w12, w24, accB[6]);                             \
            accB[7]  = fmaf(w12, w30, accB[7]);                             \
            accB[8]  = fmaf(w12, w31, accB[8]);                             \
            accB[9]  = fmaf(w12, w32, accB[9]);                             \
            accB[10] = fmaf(w12, w33, accB[10]);                            \
            accB[11] = fmaf(w12, w34, accB[11]);                            \
        } } }

    LOADCHUNK(ldA, 0);
    LOADCHUNK(ldB, 1);

    for (int chunk = 0; chunk < NCHUNK; chunk += 2) {
        BODY(chunk,     ldA, chunk + 2)
        BODY(chunk + 1, ldB, chunk + 3)
    }

    // ---- inverse norms (separate array; full sync from here on) ----
    if (hasS) {
        invnS[sidx]     = 1.0f / fmaxf(sqrtf(ssx), 1e-12f);
        invnS[sidx + 1] = 1.0f / fmaxf(sqrtf(ssy), 1e-12f);
    }
    __syncthreads();   // full drain: C reads done; invn visible; arena reusable

    constexpr int DIRD[12] = {1, 2, SW - 2, SW - 1, SW, SW + 1, SW + 2,
                              2 * SW - 2, 2 * SW - 1, 2 * SW, 2 * SW + 1, 2 * SW + 2};

    // ---- publish AFFINITY planes (each pair affinity computed ONCE) ----
    if (isPair) {
        const int qA = rA * SW + pc;
        const int qB = qA + SW;
        const float icA = invnS[qA];
        const float icB = invnS[qB];
        #pragma unroll
        for (int k = 0; k < 12; ++k) {
            const int dq = DIRD[k];
            const float simA = accA[k] * icA * invnS[qA + dq];
            const float simB = accB[k] * icB * invnS[qB + dq];
            arena[k * ND + qA] = sqrtf(fmaxf(1e-9f, fmaf(-2.0f, simA, 2.0f)));
            arena[k * ND + qB] = sqrtf(fmaxf(1e-9f, fmaf(-2.0f, simB, 2.0f)));
        }
    }
    __syncthreads();

    // ---- epilogue: compare+add only ----
    const int qp = (2 + ty) * SW + (2 + tx);
    const int lc = lblS[qp];

    float tot = 0.0f, ps = 0.0f, pn = 0.0f;
    #pragma unroll
    for (int k = 0; k < 12; ++k) {
        const int dq = DIRD[k];
        const float affF = arena[k * ND + qp];
        const float affB = arena[k * ND + qp - dq];
        const float mfF = (lblS[qp + dq] == lc) ? 1.0f : 0.0f;
        const float mfB = (lblS[qp - dq] == lc) ? 1.0f : 0.0f;
        tot += affF + affB;
        pn += mfF + mfB;
        ps = fmaf(mfF, affF, fmaf(mfB, affB, ps));
    }
    // self term: aff = sqrt(1e-9), always positive-class
    const float pos_num = pn + 1.0f;
    const float pos_sum = ps + 3.16227766e-5f;
    const float neg_num = 24.0f - pn;
    const float neg_sum = tot - ps;
    const bool boundary = (pos_num >= 4.0f) && (neg_num >= 4.0f);
    const float tri = fmaxf(0.0f,
        pos_sum / pos_num - neg_sum / fmaxf(neg_num, 1e-12f) + 0.3f);
    out[((size_t)b * Hn + (y0 + ty)) * Wn + (x0 + tx)] = boundary ? tri : 0.0f;
}

extern "C" void kernel_launch(void* const* d_in, const int* in_sizes, int n_in,
                              void* d_out, int out_size, void* d_ws, size_t ws_size,
                              hipStream_t stream) {
    const float* pred   = (const float*)d_in[0];
    const int*   target = (const int*)d_in[1];
    float*       out    = (float*)d_out;
    dim3 grid(Wn / TW, Hn / TH, Bn);   // 10 x 24 x 4 = 960 blocks
    // 1) measurement probe: pure load-pattern fetch rate + L3 warm
    fetch_probe<<<grid, NT, 0, stream>>>(pred);
    // 2) real kernel (R15 verbatim)
    guide_triplet_kernel<<<grid, NT, 0, stream>>>(pred, target, out);
}

// Round 20
// 62.878 us; speedup vs baseline: 1.8860x; 1.8860x over previous
//
#include <hip/hip_runtime.h>

// Problem constants (fixed by reference)
constexpr int Bn = 4, Cn = 64, Hn = 192, Wn = 640, HW = Hn * Wn;
constexpr int TH = 8, TW = 64;            // output tile per block
constexpr int SH = TH + 4;                // 12 tile+halo rows
constexpr int SW = TW + 4;                // 68 (even: float2 pair staging)
constexpr int NS = SH * SW;               // 816
constexpr int NP = NS / 2;                // 408 staging pairs
constexpr int PPR = SW / 2;               // 34 pairs per row
constexpr int NT = 512;                   // 1 output px/thread
constexpr int CH = 4;                     // channels staged per chunk
constexpr int NCHUNK = Cn / CH;           // 16
constexpr int DR = SH - 2;                // 10 forward-dot rows
constexpr int ND = DR * SW;               // 680 forward-domain pixels
constexpr int NPAIR = (DR / 2) * SW;      // 340 compute-pair threads
constexpr int ARENA = 12 * ND;            // 8160 floats = 32.6 KB
constexpr int NWG = 960;                  // 10 x 24 x 4
constexpr int NXCD = 8;
constexpr int CPX = NWG / NXCD;           // 120 blocks per XCD (exact)

// Relaxed barrier (T4): ds-writes visible via lgkmcnt(0); global loads stay
// in flight across the barrier (no vmcnt(0) drain, unlike __syncthreads).
#define SYNC_RELAXED() do {                                   \
    asm volatile("s_waitcnt lgkmcnt(0)" ::: "memory");        \
    __builtin_amdgcn_s_barrier();                             \
    asm volatile("" ::: "memory");                            \
} while (0)

// NOTE: min-waves-per-EU > 4 makes the allocator spill (R11). Keep 4.
__global__ __launch_bounds__(NT, 4) void guide_triplet_kernel(
    const float* __restrict__ pred,
    const int*   __restrict__ target,
    float* __restrict__ out)
{
    __shared__ float arena[ARENA];
    __shared__ float invnS[NS + 4];   // +4 pad: benign OOB publish reads
    __shared__ int   lblS[NS];

    // ---- T1: XCD-aware bijective block swizzle ----
    // Default dispatch round-robins linear wg over 8 XCDs; vertical-neighbor
    // tiles (wg +10) land on different XCDs and re-fetch shared halo rows
    // from HBM. Remap so each XCD owns a contiguous 12-y-row band (all x,
    // one b): halo rows become same-XCD L2 hits. 960 = 8*120, bijective.
    const int wg  = blockIdx.x + 10 * (blockIdx.y + 24 * blockIdx.z);
    const int pos = (wg & (NXCD - 1)) * CPX + (wg >> 3);
    const int bx  = pos % 10;
    const int byz = pos / 10;
    const int by  = byz % 24;
    const int bz  = byz / 24;

    const int x0 = bx * TW;
    const int y0 = by * TH;
    const int b  = bz;

    const int tid = threadIdx.x;
    const int tx  = tid & (TW - 1);   // 0..63
    const int ty  = tid >> 6;         // 0..7

    // ---- float2 pair staging geometry (1 pair/thread, tid < 408) ----
    const bool hasS = (tid < NP);
    const int srow = tid / PPR;               // 0..11
    const int spc  = tid - srow * PPR;        // 0..33
    const int gy = y0 + srow - 2;
    const int gx = x0 + 2 * spc - 2;          // even -> 8B aligned
    const bool okS = hasS && (gy >= 0) && (gy < Hn) && (gx >= 0) && (gx + 1 < Wn);
    const int goff = gy * Wn + gx;
    const int sidx = 2 * tid;                 // word index of the pair

    // ---- labels once (pad = -1) ----
    if (hasS) {
        int lx = -1, ly = -1;
        if (okS) {
            const int2 L = *reinterpret_cast<const int2*>(target + b * HW + goff);
            lx = L.x; ly = L.y;
        }
        lblS[sidx]     = lx;
        lblS[sidx + 1] = ly;
    }
    if (tid < 4) invnS[NS + tid] = 1.0f;      // init pad

    // ---- compute-pair mapping: thread -> pixels (rA,pc),(rA+1,pc) ----
    const bool isPair = (tid < NPAIR);
    const int pa = tid / SW;          // 0..4
    const int pc = tid - pa * SW;     // 0..67
    const int rA = 2 * pa;            // 0,2,4,6,8

    float ssx = 0.0f, ssy = 0.0f;
    float accA[12], accB[12];
    #pragma unroll
    for (int i = 0; i < 12; ++i) { accA[i] = 0.0f; accB[i] = 0.0f; }

    const float* predb = pred + (size_t)b * Cn * HW;

    float2 ldA[CH], ldB[CH];

#define LOADCHUNK(DST, CHUNK) do {                                          \
    _Pragma("unroll")                                                       \
    for (int cc = 0; cc < CH; ++cc) {                                       \
        const float* pc_ = predb + (size_t)((CHUNK) * CH + cc) * HW;        \
        float2 v = make_float2(0.f, 0.f);                                   \
        if (okS) v = *reinterpret_cast<const float2*>(pc_ + goff);          \
        DST[cc] = v;                                                        \
    } } while (0)

#define BODY(K, LD, KP2) {                                                  \
    float* sb = arena + ((K) & 1) * (CH * NS);                              \
    /* W(K): regs -> LDS (ds_write_b64), fold sumsq */                      \
    if (hasS) {                                                             \
        _Pragma("unroll")                                                   \
        for (int cc = 0; cc < CH; ++cc) {                                   \
            const float2 v = LD[cc];                                        \
            *reinterpret_cast<float2*>(&sb[cc * NS + sidx]) = v;            \
            ssx = fmaf(v.x, v.x, ssx);                                      \
            ssy = fmaf(v.y, v.y, ssy);                                      \
        } }                                                                 \
    SYNC_RELAXED();                                                         \
    /* L(K+2): depth-2 prefetch, in flight across relaxed barriers */       \
    if ((KP2) < NCHUNK) LOADCHUNK(LD, KP2);                                 \
    /* C(K): forward dots, 18 LDS words + 24 FMA per channel per pair */    \
    if (isPair) {                                                           \
        _Pragma("unroll")                                                   \
        for (int cc = 0; cc < CH; ++cc) {                                   \
            const float* s0 = sb + cc * NS + rA * SW + pc;                  \
            const float w00 = s0[0], w01 = s0[1], w02 = s0[2];              \
            const float* s1 = s0 + (SW - 2);                                \
            const float w10 = s1[0], w11 = s1[1], w12 = s1[2],              \
                        w13 = s1[3], w14 = s1[4];                           \
            const float* s2 = s1 + SW;                                      \
            const float w20 = s2[0], w21 = s2[1], w22 = s2[2],              \
                        w23 = s2[3], w24 = s2[4];                           \
            const float* s3 = s2 + SW;                                      \
            const float w30 = s3[0], w31 = s3[1], w32 = s3[2],              \
                        w33 = s3[3], w34 = s3[4];                           \
            accA[0]  = fmaf(w00, w01, accA[0]);                             \
            accA[1]  = fmaf(w00, w02, accA[1]);                             \
            accA[2]  = fmaf(w00, w10, accA[2]);                             \
            accA[3]  = fmaf(w00, w11, accA[3]);                             \
            accA[4]  = fmaf(w00, w12, accA[4]);                             \
            accA[5]  = fmaf(w00, w13, accA[5]);                             \
            accA[6]  = fmaf(w00, w14, accA[6]);                             \
            accA[7]  = fmaf(w00, w20, accA[7]);                             \
            accA[8]  = fmaf(w00, w21, accA[8]);                             \
            accA[9]  = fmaf(w00, w22, accA[9]);                             \
            accA[10] = fmaf(w00, w23, accA[10]);                            \
            accA[11] = fmaf(w00, w24, accA[11]);                            \
            accB[0]  = fmaf(w12, w13, accB[0]);                             \
            accB[1]  = fmaf(w12, w14, accB[1]);                             \
            accB[2]  = fmaf(w12, w20, accB[2]);                             \
            accB[3]  = fmaf(w12, w21, accB[3]);                             \
            accB[4]  = fmaf(w12, w22, accB[4]);                             \
            accB[5]  = fmaf(w12, w23, accB[5]);                             \
            accB[6]  = fmaf(w12, w24, accB[6]);                             \
            accB[7]  = fmaf(w12, w30, accB[7]);                             \
            accB[8]  = fmaf(w12, w31, accB[8]);                             \
            accB[9]  = fmaf(w12, w32, accB[9]);                             \
            accB[10] = fmaf(w12, w33, accB[10]);                            \
            accB[11] = fmaf(w12, w34, accB[11]);                            \
        } } }

    LOADCHUNK(ldA, 0);
    LOADCHUNK(ldB, 1);

    for (int chunk = 0; chunk < NCHUNK; chunk += 2) {
        BODY(chunk,     ldA, chunk + 2)
        BODY(chunk + 1, ldB, chunk + 3)
    }

    // ---- inverse norms (separate array; full sync from here on) ----
    if (hasS) {
        invnS[sidx]     = 1.0f / fmaxf(sqrtf(ssx), 1e-12f);
        invnS[sidx + 1] = 1.0f / fmaxf(sqrtf(ssy), 1e-12f);
    }
    __syncthreads();   // full drain: C reads done; invn visible; arena reusable

    constexpr int DIRD[12] = {1, 2, SW - 2, SW - 1, SW, SW + 1, SW + 2,
                              2 * SW - 2, 2 * SW - 1, 2 * SW, 2 * SW + 1, 2 * SW + 2};

    // ---- publish AFFINITY planes (each pair affinity computed ONCE) ----
    if (isPair) {
        const int qA = rA * SW + pc;
        const int qB = qA + SW;
        const float icA = invnS[qA];
        const float icB = invnS[qB];
        #pragma unroll
        for (int k = 0; k < 12; ++k) {
            const int dq = DIRD[k];
            const float simA = accA[k] * icA * invnS[qA + dq];
            const float simB = accB[k] * icB * invnS[qB + dq];
            arena[k * ND + qA] = sqrtf(fmaxf(1e-9f, fmaf(-2.0f, simA, 2.0f)));
            arena[k * ND + qB] = sqrtf(fmaxf(1e-9f, fmaf(-2.0f, simB, 2.0f)));
        }
    }
    __syncthreads();

    // ---- epilogue: compare+add only ----
    const int qp = (2 + ty) * SW + (2 + tx);
    const int lc = lblS[qp];

    float tot = 0.0f, ps = 0.0f, pn = 0.0f;
    #pragma unroll
    for (int k = 0; k < 12; ++k) {
        const int dq = DIRD[k];
        const float affF = arena[k * ND + qp];
        const float affB = arena[k * ND + qp - dq];
        const float mfF = (lblS[qp + dq] == lc) ? 1.0f : 0.0f;
        const float mfB = (lblS[qp - dq] == lc) ? 1.0f : 0.0f;
        tot += affF + affB;
        pn += mfF + mfB;
        ps = fmaf(mfF, affF, fmaf(mfB, affB, ps));
    }
    // self term: aff = sqrt(1e-9), always positive-class
    const float pos_num = pn + 1.0f;
    const float pos_sum = ps + 3.16227766e-5f;
    const float neg_num = 24.0f - pn;
    const float neg_sum = tot - ps;
    const bool boundary = (pos_num >= 4.0f) && (neg_num >= 4.0f);
    const float tri = fmaxf(0.0f,
        pos_sum / pos_num - neg_sum / fmaxf(neg_num, 1e-12f) + 0.3f);
    out[((size_t)b * Hn + (y0 + ty)) * Wn + (x0 + tx)] = boundary ? tri : 0.0f;
}

extern "C" void kernel_launch(void* const* d_in, const int* in_sizes, int n_in,
                              void* d_out, int out_size, void* d_ws, size_t ws_size,
                              hipStream_t stream) {
    const float* pred   = (const float*)d_in[0];
    const int*   target = (const int*)d_in[1];
    float*       out    = (float*)d_out;
    dim3 grid(Wn / TW, Hn / TH, Bn);   // 10 x 24 x 4 = 960 blocks
    guide_triplet_kernel<<<grid, NT, 0, stream>>>(pred, target, out);
}